// Round 18
// baseline (285.579 us; speedup 1.0000x reference)
//
#include <hip/hip_runtime.h>
#include <hip/hip_bf16.h>
#include <stdint.h>

typedef __attribute__((ext_vector_type(8))) __bf16 bf16x8;
typedef __attribute__((ext_vector_type(4))) float f32x4;
typedef __attribute__((ext_vector_type(4))) unsigned u32x4;
typedef __attribute__((ext_vector_type(2))) unsigned u32x2;

#define DEVINL static __device__ __forceinline__

#if __has_builtin(__builtin_amdgcn_permlane32_swap) && __has_builtin(__builtin_amdgcn_permlane16_swap)
#define HAVE_PERMLANE_SWAP 1
#else
#define HAVE_PERMLANE_SWAP 0
#endif

constexpr int WSZ = 7, EXPAND = 3, NHEAD = 12, DIM = 384, HDIM = 32;
constexpr int WS2 = 49, NKEY = 132, NTOK = 181;
constexpr int BB = 2, HH = 168, WW = 168;
constexpr int NWY = HH / WSZ, NWX = WW / WSZ;        // 24, 24
constexpr int NWIN = BB * NWY * NWX;                 // 1152
constexpr int MTOT = BB * HH * WW;                   // 56448
constexpr float SCALE = 0.1767766952966369f;         // 32^-0.5
constexpr float LOG2E = 1.4426950408889634f;
constexpr size_t PLANE = (size_t)MTOT * DIM;         // 21,676,032
constexpr int NQKV = 3 * DIM * DIM;                  // 442,368
constexpr int NPROJ = DIM * DIM;                     // 147,456
constexpr int BIAS_ELEMS = NHEAD * 64 * 192;         // 147,456 f32 (590 KB)
constexpr int HPB = 4;                               // heads per attn block
constexpr int ATTN_GRID = NWIN * NHEAD / HPB;        // 3456

// raw v_exp_f32: computes 2^x in one TRANS-pipe op (exp2f = precise OCML, ~10 ops)
DEVINL float fast_exp2(float x) {
  float r;
  asm("v_exp_f32 %0, %1" : "=v"(r) : "v"(x));
  return r;
}

// ---- packed token offset table: (dy+8)<<5 | (dx+8), window-relative ----
struct TokTab { int v[192]; };
constexpr TokTab make_toktab() {
  TokTab tt{};
  for (int t = 0; t < 192; ++t) tt.v[t] = 8 * 32 + 8;
  for (int t = 0; t < WS2; ++t) tt.v[t] = (t / WSZ + 8) * 32 + (t % WSZ + 8);
  int n = WS2;
  for (int quad = 0; quad < 4; ++quad)
    for (int i = 0; i < WSZ; ++i)
      for (int j = 0; j < WSZ; ++j) {
        bool drop;
        if (quad == 0)      drop = (i < WSZ - EXPAND) && (j < WSZ - EXPAND);
        else if (quad == 1) drop = (i < WSZ - EXPAND) && (j >= EXPAND);
        else if (quad == 2) drop = (i >= EXPAND)      && (j < WSZ - EXPAND);
        else                drop = (i >= EXPAND)      && (j >= EXPAND);
        if (!drop) {
          int dy = (quad < 2)        ? i + EXPAND : i - EXPAND;
          int dx = ((quad & 1) == 0) ? j + EXPAND : j - EXPAND;
          tt.v[n++] = (dy + 8) * 32 + (dx + 8);
        }
      }
  return tt;
}
__device__ constexpr TokTab TOKTAB = make_toktab();

DEVINL int xcd_swizzle(int bid, int nwg) {
  int q8 = nwg >> 3, r8 = nwg & 7;
  int xcd = bid & 7, ii = bid >> 3;
  return (xcd < r8 ? xcd * (q8 + 1) : r8 * (q8 + 1) + (xcd - r8) * q8) + ii;
}

// pixel-row -> window-ordered row permutation (fallback path only)
DEVINL int qperm(int m) {
  int b = m / (HH * WW);
  int rem = m - b * (HH * WW);
  int y = rem / WW;
  int x = rem - y * WW;
  int win = b * (NWY * NWX) + (y / WSZ) * NWX + (x / WSZ);
  int qi = (y % WSZ) * WSZ + (x % WSZ);
  return win * WS2 + qi;
}

DEVINL bf16x8 load8_cvt(const float* p) {
  float4 a = *(const float4*)p;
  float4 b = *(const float4*)(p + 4);
  bf16x8 r = {(__bf16)a.x, (__bf16)a.y, (__bf16)a.z, (__bf16)a.w,
              (__bf16)b.x, (__bf16)b.y, (__bf16)b.z, (__bf16)b.w};
  return r;
}
DEVINL bf16x8 load8_cvt(const __bf16* p) { return *(const bf16x8*)p; }

DEVINL void gload16(const __bf16* g, __bf16* l) {
  __builtin_amdgcn_global_load_lds(
      (const __attribute__((address_space(1))) unsigned int*)g,
      (__attribute__((address_space(3))) unsigned int*)l, 16, 0, 0);
}

DEVINL unsigned pack2(float a, float b) {
  unsigned short ua = __builtin_bit_cast(unsigned short, (__bf16)a);
  unsigned short ub = __builtin_bit_cast(unsigned short, (__bf16)b);
  return ((unsigned)ub << 16) | ua;
}

// ---- fused: f32->bf16 convert (x, w_qkv, w_proj) + bias table build ----
// biasTab [h][q(64)][k(192)] f32, PRE-SCALED by log2(e) (exp2-domain softmax):
// k>=181 -> -60*log2e (key mask), q>=49 -> -60*log2e. QK^T MFMA C-operand.
constexpr int XG8 = PLANE / 8;            // 2,709,504
constexpr int QG8 = NQKV / 8;             // 55,296
constexpr int PG8 = NPROJ / 8;            // 18,432
constexpr int CVT_GRID = (XG8 + QG8 + PG8) / 256;  // 10,872 exact
constexpr int BIAS_GRID = BIAS_ELEMS / 256;        // 576

__global__ __launch_bounds__(256) void cvt_bias(
    const float* __restrict__ a, const float* __restrict__ b, const float* __restrict__ c,
    __bf16* __restrict__ da, __bf16* __restrict__ db, __bf16* __restrict__ dc,
    const float* __restrict__ rpbT, const float* __restrict__ rpbN,
    float* __restrict__ biasTab, int cvtBlocks) {
  int bid = blockIdx.x;
  if (bid < cvtBlocks) {
    int i = bid * 256 + threadIdx.x;
    const float* s; __bf16* d; int j;
    if (i < XG8)            { s = a; d = da; j = i; }
    else if (i < XG8 + QG8) { s = b; d = db; j = i - XG8; }
    else                    { s = c; d = dc; j = i - XG8 - QG8; }
    *(bf16x8*)(d + (size_t)j * 8) = load8_cvt(s + (size_t)j * 8);
  } else {
    int i = (bid - cvtBlocks) * 256 + threadIdx.x;   // ((h*64)+q)*192+k
    int k = i % 192;
    int rest = i / 192;
    int q = rest & 63, h = rest >> 6;
    float v = -60.f;
    if (k < NTOK && q < WS2) {
      if (k < WS2) {
        int iq = q / 7, jq = q - iq * 7, ik = k / 7, jk = k - ik * 7;
        v = rpbT[((iq - ik + 6) * 13 + (jq - jk + 6)) * NHEAD + h];
      } else {
        v = rpbN[(h * WS2 + q) * NKEY + (k - WS2)];
      }
    }
    biasTab[i] = v * LOG2E;
  }
}

// ---- fast GEMM (bf16 A and Bt, global_load_lds staging, m97 structure) ----
// scale0 multiplies output 0 (sel==0) after bias add (used to pre-scale Q).
template <typename OT>
__global__ __launch_bounds__(256) void gemm_fast(
    const __bf16* __restrict__ A, const __bf16* __restrict__ Bt,
    const float* __restrict__ bias,
    OT* __restrict__ O0, OT* __restrict__ O1, OT* __restrict__ O2,
    int K, int NoutPer, int nxt, float scale0) {
  __shared__ __bf16 As[128 * 64];
  __shared__ __bf16 Bs[128 * 64];

  const int t = threadIdx.x;
  const int wv = t >> 6, ln = t & 63;
  const int lc = ln & 15, kg = (ln >> 4) * 8;
  const int wm = wv >> 1, wn = wv & 1;
  const int L = xcd_swizzle(blockIdx.x, gridDim.x);
  const int mt = L / nxt, nt = L - mt * nxt;
  const int m0 = mt * 128, n0 = nt * 128;

  const __bf16* ga = A + (size_t)(m0 + wv * 8 + (ln >> 3)) * K + (ln & 7) * 8;
  const __bf16* gb = Bt + (size_t)(n0 + wv * 8 + (ln >> 3)) * K + (ln & 7) * 8;

  f32x4 acc[4][4] = {};

  for (int kt = 0; kt < K; kt += 64) {
#pragma unroll
    for (int i = 0; i < 4; ++i) {
      gload16(ga + (size_t)(i * 32) * K + kt, As + (i * 32 + wv * 8) * 64);
      gload16(gb + (size_t)(i * 32) * K + kt, Bs + (i * 32 + wv * 8) * 64);
    }
    __syncthreads();
#pragma unroll
    for (int ks = 0; ks < 2; ++ks) {
      bf16x8 af[4], bb[4];
#pragma unroll
      for (int m = 0; m < 4; ++m)
        af[m] = *(const bf16x8*)&As[(wm * 64 + m * 16 + lc) * 64 + ks * 32 + kg];
#pragma unroll
      for (int n = 0; n < 4; ++n)
        bb[n] = *(const bf16x8*)&Bs[(wn * 64 + n * 16 + lc) * 64 + ks * 32 + kg];
#pragma unroll
      for (int m = 0; m < 4; ++m)
#pragma unroll
        for (int n = 0; n < 4; ++n)
          acc[m][n] = __builtin_amdgcn_mfma_f32_16x16x32_bf16(af[m], bb[n], acc[m][n], 0, 0, 0);
    }
    __syncthreads();
  }

  OT* outs[3] = {O0, O1, O2};
#pragma unroll
  for (int n = 0; n < 4; ++n) {
    int col = n0 + wn * 64 + n * 16 + lc;
    int sel = col / NoutPer;
    int c = col - sel * NoutPer;
    float bv = bias[col];
    float sc = (sel == 0) ? scale0 : 1.f;
    OT* op = outs[sel];
#pragma unroll
    for (int m = 0; m < 4; ++m) {
      int row = m0 + wm * 64 + m * 16 + (ln >> 4) * 4;
#pragma unroll
      for (int r = 0; r < 4; ++r)
        op[(size_t)(row + r) * NoutPer + c] = (OT)((acc[m][n][r] + bv) * sc);
    }
  }
}

// ---- fallback GEMM (f32/bf16 A reg-staged, optional qperm) ----
template <typename AT, typename OT>
__global__ __launch_bounds__(256) void gemm_bt(
    const AT* __restrict__ A, const float* __restrict__ Bt,
    const float* __restrict__ bias,
    OT* __restrict__ O0, OT* __restrict__ O1, OT* __restrict__ O2,
    int K, int NoutPer, int qPerm, int nxt, float scale0) {
  __shared__ __bf16 As[128 * 64];
  __shared__ __bf16 Bs[128 * 64];

  const int t = threadIdx.x;
  const int wv = t >> 6, ln = t & 63;
  const int lc = ln & 15, kg = (ln >> 4) * 8;
  const int wm = wv >> 1, wn = wv & 1;
  const int L = xcd_swizzle(blockIdx.x, gridDim.x);
  const int mt = L / nxt, nt = L - mt * nxt;
  const int m0 = mt * 128, n0 = nt * 128;
  const int srow = t >> 3, scol = (t & 7) * 8;

  f32x4 acc[4][4] = {};

  for (int kt = 0; kt < K; kt += 64) {
#pragma unroll
    for (int i = 0; i < 4; ++i) {
      int row = i * 32 + srow;
      *(bf16x8*)&As[row * 64 + scol] = load8_cvt(A + (size_t)(m0 + row) * K + kt + scol);
      *(bf16x8*)&Bs[row * 64 + scol] = load8_cvt(Bt + (size_t)(n0 + row) * K + kt + scol);
    }
    __syncthreads();
#pragma unroll
    for (int ks = 0; ks < 2; ++ks) {
      bf16x8 af[4], bb[4];
#pragma unroll
      for (int m = 0; m < 4; ++m)
        af[m] = *(const bf16x8*)&As[(wm * 64 + m * 16 + lc) * 64 + ks * 32 + kg];
#pragma unroll
      for (int n = 0; n < 4; ++n)
        bb[n] = *(const bf16x8*)&Bs[(wn * 64 + n * 16 + lc) * 64 + ks * 32 + kg];
#pragma unroll
      for (int m = 0; m < 4; ++m)
#pragma unroll
        for (int n = 0; n < 4; ++n)
          acc[m][n] = __builtin_amdgcn_mfma_f32_16x16x32_bf16(af[m], bb[n], acc[m][n], 0, 0, 0);
    }
    __syncthreads();
  }

  OT* outs[3] = {O0, O1, O2};
#pragma unroll
  for (int n = 0; n < 4; ++n) {
    int col = n0 + wn * 64 + n * 16 + lc;
    int sel = col / NoutPer;
    int c = col - sel * NoutPer;
    float bv = bias[col];
    float sc = (qPerm && sel == 0) ? scale0 : 1.f;
    OT* op = outs[sel];
    bool perm = qPerm && (sel == 0);
#pragma unroll
    for (int m = 0; m < 4; ++m) {
      int row = m0 + wm * 64 + m * 16 + (ln >> 4) * 4;
#pragma unroll
      for (int r = 0; r < 4; ++r) {
        int rr = row + r;
        int orow = perm ? qperm(rr) : rr;
        op[(size_t)orow * NoutPer + c] = (OT)((acc[m][n][r] + bv) * sc);
      }
    }
  }
}

// ---- one head's full compute (QK^T + softmax + PV + epilogue) ----
// Verified r16 numerics, unchanged.
DEVINL void attn_head_compute(
    bf16x8 aq, const float* __restrict__ btab,
    const __bf16* Ks, const __bf16* Vt,
    int win, int hb, int wv, int lc, int lg,
    __bf16* __restrict__ Og) {
  // swapped QK^T: lane holds col q = wv*16+lc, rows k = nf*16 + lg*4 + r
  f32x4 s[12];
  __builtin_amdgcn_s_setprio(1);
#pragma unroll
  for (int nf = 0; nf < 12; ++nf) {
    bf16x8 kf = *(const bf16x8*)&Ks[(nf * 16 + lc) * 40 + lg * 8];
    f32x4 c = *(const f32x4*)&btab[nf * 16 + lg * 4];
    s[nf] = __builtin_amdgcn_mfma_f32_16x16x32_bf16(kf, aq, c, 0, 0, 0);
  }
  __builtin_amdgcn_s_setprio(0);

  // softmax (log2 domain, raw v_exp_f32)
  float mx = -1e30f;
#pragma unroll
  for (int nf = 0; nf < 12; ++nf)
#pragma unroll
    for (int r = 0; r < 4; ++r) mx = fmaxf(mx, s[nf][r]);
  mx = fmaxf(mx, __shfl_xor(mx, 16));
  mx = fmaxf(mx, __shfl_xor(mx, 32));

  float sum = 0.f;
#pragma unroll
  for (int nf = 0; nf < 12; ++nf)
#pragma unroll
    for (int r = 0; r < 4; ++r) {
      float e = fast_exp2(s[nf][r] - mx);
      s[nf][r] = e;
      sum += e;
    }
  sum += __shfl_xor(sum, 16);
  sum += __shfl_xor(sum, 32);
  float inv = 1.f / sum;

  // PV with in-register P handoff (permlane builtins — r16-verified).
  const int s0 = lc + ((lg & 1) << 5);
  const int s1 = s0 + 16;
  const bool lo = (lg < 2);
  f32x4 o[2] = {{}, {}};
  __builtin_amdgcn_s_setprio(1);
#pragma unroll
  for (int ks = 0; ks < 6; ++ks) {
    int na = 2 * ks, nb = 2 * ks + 1;
    unsigned la0 = pack2(s[na][0], s[na][1]);
    unsigned la1 = pack2(s[na][2], s[na][3]);
    unsigned lb0 = pack2(s[nb][0], s[nb][1]);
    unsigned lb1 = pack2(s[nb][2], s[nb][3]);
    u32x4 wvec;
#if HAVE_PERMLANE_SWAP
    {
      u32x2 r0 = __builtin_amdgcn_permlane32_swap(la0, lb0, false, false);
      u32x2 r1 = __builtin_amdgcn_permlane16_swap(r0[0], r0[1], false, false);
      u32x2 r2 = __builtin_amdgcn_permlane32_swap(la1, lb1, false, false);
      u32x2 r3 = __builtin_amdgcn_permlane16_swap(r2[0], r2[1], false, false);
      wvec[0] = r1[0];   // w0 = [A0,A2,B0,B2]
      wvec[1] = r3[0];   // w1
      wvec[2] = r1[1];   // w2 = [A1,A3,B1,B3]
      wvec[3] = r3[1];   // w3
    }
#else
    {
      unsigned xa0 = __shfl(la0, s0);
      unsigned xb0 = __shfl(lb0, s0);
      unsigned xa1 = __shfl(la1, s0);
      unsigned xb1 = __shfl(lb1, s0);
      unsigned ya0 = __shfl(la0, s1);
      unsigned yb0 = __shfl(lb0, s1);
      unsigned ya1 = __shfl(la1, s1);
      unsigned yb1 = __shfl(lb1, s1);
      wvec[0] = lo ? xa0 : xb0;
      wvec[1] = lo ? xa1 : xb1;
      wvec[2] = lo ? ya0 : yb0;
      wvec[3] = lo ? ya1 : yb1;
    }
#endif
    bf16x8 ap = __builtin_bit_cast(bf16x8, wvec);
#pragma unroll
    for (int nf = 0; nf < 2; ++nf) {
      int rowV = nf * 16 + lc;
      int cv = ks * 32 + lg * 8 + (rowV >> 3) * 16; if (cv >= 200) cv -= 200;
      bf16x8 bv = *(const bf16x8*)&Vt[rowV * 200 + cv];
      o[nf] = __builtin_amdgcn_mfma_f32_16x16x32_bf16(ap, bv, o[nf], 0, 0, 0);
    }
  }
  __builtin_amdgcn_s_setprio(0);

  // epilogue: output rows q = wv*16 + lg*4 + r; 1/sum via shfl
  float invr[4];
#pragma unroll
  for (int r = 0; r < 4; ++r) invr[r] = __shfl(inv, lg * 4 + r);

#pragma unroll
  for (int nf = 0; nf < 2; ++nf)
#pragma unroll
    for (int r = 0; r < 4; ++r) {
      int qo = wv * 16 + lg * 4 + r;
      if (qo < WS2)
        Og[(size_t)(win * WS2 + qo) * DIM + hb + nf * 16 + lc] =
            (__bf16)(o[nf][r] * invr[r]);
    }
}

// ---- attention v5: 4 heads per block, one-ahead register pipeline ----
// stage h0 -> barrier -> loop { issue h(i+1) loads -> compute h(i) ->
// barrier -> write LDS h(i+1) -> barrier }. Cold-stage paid once per 4 heads.
// LDS = Ks[192][40] + Vt[32][200] = 28,160 B. Qg pre-scaled by SCALE*log2e;
// biasTab in log2e domain. Og window-ordered.
template <int QPIX>
__global__ __launch_bounds__(256, 4) void attn_win(
    const __bf16* __restrict__ Qg, const __bf16* __restrict__ Kg, const __bf16* __restrict__ Vg,
    const float* __restrict__ biasTab,
    __bf16* __restrict__ Og) {
  __shared__ __bf16 Ks[192 * 40];   // K row-major, stride 40 (bank-spread)
  __shared__ __bf16 Vt[32 * 200];   // V^T rotated: col = (token + (d>>3)*16) % 200

  const int S = xcd_swizzle(blockIdx.x, ATTN_GRID);
  const int win = S / (NHEAD / HPB);
  const int hq = S - win * (NHEAD / HPB);
  const int hbase = hq * HPB * HDIM;
  const int b = win / (NWY * NWX);
  const int wrem = win - b * (NWY * NWX);
  const int wy = wrem / NWX, wx = wrem - wy * NWX;
  const int y0 = wy * WSZ, x0 = wx * WSZ;

  const int t = threadIdx.x;
  const int wv = t >> 6, ln = t & 63;
  const int lc = ln & 15, lg = ln >> 4;
  const int q = wv * 16 + lc;        // this lane's q (output col in swapped QK^T)

  // per-thread staging offsets (token base + ch*8, WITHOUT head column)
  int offs[3]; bool val[3]; int toks[3], chs[3];
#pragma unroll
  for (int it = 0; it < 3; ++it) {
    int idx = t + it * 256;
    int token = idx >> 2, ch = idx & 3;
    int pk = TOKTAB.v[token];
    int yy = y0 + (pk >> 5) - 8;
    int xx = x0 + (pk & 31) - 8;
    if (yy < 0) yy += HH; else if (yy >= HH) yy -= HH;
    if (xx < 0) xx += WW; else if (xx >= WW) xx -= WW;
    offs[it] = ((b * HH + yy) * WW + xx) * DIM + ch * 8;
    val[it] = token < NTOK;
    toks[it] = token; chs[it] = ch;
  }

  // Q base offset (head-independent)
  int qoff = 0;
  if (q < WS2) {
    if (QPIX) {
      int pk = TOKTAB.v[q];
      int yy = y0 + (pk >> 5) - 8, xx = x0 + (pk & 31) - 8;
      qoff = ((b * HH + yy) * WW + xx) * DIM;
    } else {
      qoff = (win * WS2 + q) * DIM;
    }
  }

  // ---- head 0: load K/V into regs, write LDS ----
  bf16x8 kv[3], vv[3];
#pragma unroll
  for (int it = 0; it < 3; ++it) {
    kv[it] = bf16x8{}; vv[it] = bf16x8{};
    if (val[it]) {
      kv[it] = *(const bf16x8*)(Kg + (size_t)offs[it] + hbase);
      vv[it] = *(const bf16x8*)(Vg + (size_t)offs[it] + hbase);
    }
  }
  bf16x8 aqc = {}, aqn = {};
  if (q < WS2) aqc = *(const bf16x8*)(Qg + (size_t)qoff + hbase + lg * 8);

#pragma unroll
  for (int it = 0; it < 3; ++it) {
    *(bf16x8*)&Ks[toks[it] * 40 + chs[it] * 8] = kv[it];
    int col2 = toks[it] + chs[it] * 16; if (col2 >= 200) col2 -= 200;
#pragma unroll
    for (int e = 0; e < 8; ++e)
      Vt[(chs[it] * 8 + e) * 200 + col2] = vv[it][e];
  }
  __syncthreads();                       // LDS for head 0 ready

#pragma unroll
  for (int i = 0; i < HPB; ++i) {
    const int hb = hbase + i * HDIM;
    // issue next head's global loads EARLY (hide HBM under compute)
    if (i < HPB - 1) {
#pragma unroll
      for (int it = 0; it < 3; ++it) {
        kv[it] = bf16x8{}; vv[it] = bf16x8{};
        if (val[it]) {
          kv[it] = *(const bf16x8*)(Kg + (size_t)offs[it] + hb + HDIM);
          vv[it] = *(const bf16x8*)(Vg + (size_t)offs[it] + hb + HDIM);
        }
      }
      aqn = bf16x8{};
      if (q < WS2) aqn = *(const bf16x8*)(Qg + (size_t)qoff + hb + HDIM + lg * 8);
    }

    attn_head_compute(aqc, biasTab + ((size_t)(hq * HPB + i) * 64 + q) * 192,
                      Ks, Vt, win, hb, wv, lc, lg, Og);
    __syncthreads();                     // all waves done reading current LDS

    if (i < HPB - 1) {
#pragma unroll
      for (int it = 0; it < 3; ++it) {
        *(bf16x8*)&Ks[toks[it] * 40 + chs[it] * 8] = kv[it];
        int col2 = toks[it] + chs[it] * 16; if (col2 >= 200) col2 -= 200;
#pragma unroll
        for (int e = 0; e < 8; ++e)
          Vt[(chs[it] * 8 + e) * 200 + col2] = vv[it][e];
      }
      __syncthreads();
      aqc = aqn;
    }
  }
}

extern "C" void kernel_launch(void* const* d_in, const int* in_sizes, int n_in,
                              void* d_out, int out_size, void* d_ws, size_t ws_size,
                              hipStream_t stream) {
  const float* x      = (const float*)d_in[0];
  const float* w_qkv  = (const float*)d_in[1];
  const float* b_qkv  = (const float*)d_in[2];
  const float* w_proj = (const float*)d_in[3];
  const float* b_proj = (const float*)d_in[4];
  const float* rpbT   = (const float*)d_in[5];
  const float* rpbN   = (const float*)d_in[6];

  float* out = (float*)d_out;
  __bf16* k_ws = (__bf16*)d_out;           // d_out = 2 bf16 planes (K, V)
  __bf16* v_ws = k_ws + PLANE;

  const size_t fast_elems = 2 * PLANE + NQKV + NPROJ;
  const size_t fast_ws_bytes = fast_elems * 2 + BIAS_ELEMS * 4;   // ~88.5 MB
  const float qscale = SCALE * LOG2E;

  if (ws_size >= fast_ws_bytes) {
    // FAST PATH: pre-convert to bf16, global_load_lds GEMMs, no row permute.
    __bf16* xo_bf   = (__bf16*)d_ws;       // x_bf during gemm1; O plane after
    __bf16* q_bf    = xo_bf + PLANE;       // Q, pixel-ordered, pre-scaled
    __bf16* wqkv_b  = q_bf + PLANE;
    __bf16* wproj_b = wqkv_b + NQKV;
    float*  biasTab = (float*)(wproj_b + NPROJ);

    cvt_bias<<<dim3(CVT_GRID + BIAS_GRID), 256, 0, stream>>>(
        x, w_qkv, w_proj, xo_bf, wqkv_b, wproj_b, rpbT, rpbN, biasTab, CVT_GRID);

    gemm_fast<__bf16><<<dim3((1152 / 128) * (MTOT / 128)), 256, 0, stream>>>(
        xo_bf, wqkv_b, b_qkv, q_bf, k_ws, v_ws, DIM, DIM, 1152 / 128, qscale);

    attn_win<1><<<dim3(ATTN_GRID), 256, 0, stream>>>(
        q_bf, k_ws, v_ws, biasTab, xo_bf);   // O overwrites dead x_bf

    gemm_fast<float><<<dim3((384 / 128) * (MTOT / 128)), 256, 0, stream>>>(
        xo_bf, wproj_b, b_proj, out, out, out, DIM, DIM, 384 / 128, 1.f);
  } else {
    // FALLBACK: f32 reg-staged GEMM1 with qperm epilogue (Q pre-scaled).
    __bf16* qo_ws   = (__bf16*)d_ws;
    float*  biasTab = (float*)(qo_ws + PLANE);

    cvt_bias<<<dim3(BIAS_GRID), 256, 0, stream>>>(
        x, w_qkv, w_proj, nullptr, nullptr, nullptr, rpbT, rpbN, biasTab, 0);

    gemm_bt<float, __bf16><<<dim3((1152 / 128) * (MTOT / 128)), 256, 0, stream>>>(
        x, w_qkv, b_qkv, qo_ws, k_ws, v_ws, DIM, DIM, 1, 1152 / 128, qscale);

    attn_win<0><<<dim3(ATTN_GRID), 256, 0, stream>>>(
        qo_ws, k_ws, v_ws, biasTab, qo_ws);

    gemm_bt<__bf16, float><<<dim3((384 / 128) * (MTOT / 128)), 256, 0, stream>>>(
        qo_ws, w_proj, b_proj, out, out, out, DIM, DIM, 0, 384 / 128, 1.f);
  }
}

// Round 19
// 262.958 us; speedup vs baseline: 1.0860x; 1.0860x over previous
//
#include <hip/hip_runtime.h>
#include <hip/hip_bf16.h>
#include <stdint.h>

typedef __attribute__((ext_vector_type(8))) __bf16 bf16x8;
typedef __attribute__((ext_vector_type(4))) float f32x4;
typedef __attribute__((ext_vector_type(4))) unsigned u32x4;
typedef __attribute__((ext_vector_type(2))) unsigned u32x2;

#define DEVINL static __device__ __forceinline__

#if __has_builtin(__builtin_amdgcn_permlane32_swap) && __has_builtin(__builtin_amdgcn_permlane16_swap)
#define HAVE_PERMLANE_SWAP 1
#else
#define HAVE_PERMLANE_SWAP 0
#endif

constexpr int WSZ = 7, EXPAND = 3, NHEAD = 12, DIM = 384, HDIM = 32;
constexpr int WS2 = 49, NKEY = 132, NTOK = 181;
constexpr int BB = 2, HH = 168, WW = 168;
constexpr int NWY = HH / WSZ, NWX = WW / WSZ;        // 24, 24
constexpr int NWIN = BB * NWY * NWX;                 // 1152
constexpr int MTOT = BB * HH * WW;                   // 56448
constexpr float SCALE = 0.1767766952966369f;         // 32^-0.5
constexpr float LOG2E = 1.4426950408889634f;
constexpr size_t PLANE = (size_t)MTOT * DIM;         // 21,676,032
constexpr int NQKV = 3 * DIM * DIM;                  // 442,368
constexpr int NPROJ = DIM * DIM;                     // 147,456
constexpr int BIAS_ELEMS = NHEAD * 64 * 192;         // 147,456 f32 (590 KB)
constexpr int ATTN_GRID = NWIN * NHEAD / 2;          // 6912 (2 heads/block)

// raw v_exp_f32: computes 2^x in one TRANS-pipe op (exp2f = precise OCML, ~10 ops)
DEVINL float fast_exp2(float x) {
  float r;
  asm("v_exp_f32 %0, %1" : "=v"(r) : "v"(x));
  return r;
}

// ---- packed token offset table: (dy+8)<<5 | (dx+8), window-relative ----
struct TokTab { int v[192]; };
constexpr TokTab make_toktab() {
  TokTab tt{};
  for (int t = 0; t < 192; ++t) tt.v[t] = 8 * 32 + 8;
  for (int t = 0; t < WS2; ++t) tt.v[t] = (t / WSZ + 8) * 32 + (t % WSZ + 8);
  int n = WS2;
  for (int quad = 0; quad < 4; ++quad)
    for (int i = 0; i < WSZ; ++i)
      for (int j = 0; j < WSZ; ++j) {
        bool drop;
        if (quad == 0)      drop = (i < WSZ - EXPAND) && (j < WSZ - EXPAND);
        else if (quad == 1) drop = (i < WSZ - EXPAND) && (j >= EXPAND);
        else if (quad == 2) drop = (i >= EXPAND)      && (j < WSZ - EXPAND);
        else                drop = (i >= EXPAND)      && (j >= EXPAND);
        if (!drop) {
          int dy = (quad < 2)        ? i + EXPAND : i - EXPAND;
          int dx = ((quad & 1) == 0) ? j + EXPAND : j - EXPAND;
          tt.v[n++] = (dy + 8) * 32 + (dx + 8);
        }
      }
  return tt;
}
__device__ constexpr TokTab TOKTAB = make_toktab();

DEVINL int xcd_swizzle(int bid, int nwg) {
  int q8 = nwg >> 3, r8 = nwg & 7;
  int xcd = bid & 7, ii = bid >> 3;
  return (xcd < r8 ? xcd * (q8 + 1) : r8 * (q8 + 1) + (xcd - r8) * q8) + ii;
}

// pixel-row -> window-ordered row permutation (fallback path only)
DEVINL int qperm(int m) {
  int b = m / (HH * WW);
  int rem = m - b * (HH * WW);
  int y = rem / WW;
  int x = rem - y * WW;
  int win = b * (NWY * NWX) + (y / WSZ) * NWX + (x / WSZ);
  int qi = (y % WSZ) * WSZ + (x % WSZ);
  return win * WS2 + qi;
}

DEVINL bf16x8 load8_cvt(const float* p) {
  float4 a = *(const float4*)p;
  float4 b = *(const float4*)(p + 4);
  bf16x8 r = {(__bf16)a.x, (__bf16)a.y, (__bf16)a.z, (__bf16)a.w,
              (__bf16)b.x, (__bf16)b.y, (__bf16)b.z, (__bf16)b.w};
  return r;
}
DEVINL bf16x8 load8_cvt(const __bf16* p) { return *(const bf16x8*)p; }

DEVINL void gload16(const __bf16* g, __bf16* l) {
  __builtin_amdgcn_global_load_lds(
      (const __attribute__((address_space(1))) unsigned int*)g,
      (__attribute__((address_space(3))) unsigned int*)l, 16, 0, 0);
}

DEVINL unsigned pack2(float a, float b) {
  unsigned short ua = __builtin_bit_cast(unsigned short, (__bf16)a);
  unsigned short ub = __builtin_bit_cast(unsigned short, (__bf16)b);
  return ((unsigned)ub << 16) | ua;
}

// ---- fused: f32->bf16 convert (x, w_qkv, w_proj) + bias table build ----
// biasTab [h][q(64)][k(192)] f32, PRE-SCALED by log2(e) (exp2-domain softmax):
// k>=181 -> -60*log2e (key mask), q>=49 -> -60*log2e. QK^T MFMA C-operand.
constexpr int XG8 = PLANE / 8;            // 2,709,504
constexpr int QG8 = NQKV / 8;             // 55,296
constexpr int PG8 = NPROJ / 8;            // 18,432
constexpr int CVT_GRID = (XG8 + QG8 + PG8) / 256;  // 10,872 exact
constexpr int BIAS_GRID = BIAS_ELEMS / 256;        // 576

__global__ __launch_bounds__(256) void cvt_bias(
    const float* __restrict__ a, const float* __restrict__ b, const float* __restrict__ c,
    __bf16* __restrict__ da, __bf16* __restrict__ db, __bf16* __restrict__ dc,
    const float* __restrict__ rpbT, const float* __restrict__ rpbN,
    float* __restrict__ biasTab, int cvtBlocks) {
  int bid = blockIdx.x;
  if (bid < cvtBlocks) {
    int i = bid * 256 + threadIdx.x;
    const float* s; __bf16* d; int j;
    if (i < XG8)            { s = a; d = da; j = i; }
    else if (i < XG8 + QG8) { s = b; d = db; j = i - XG8; }
    else                    { s = c; d = dc; j = i - XG8 - QG8; }
    *(bf16x8*)(d + (size_t)j * 8) = load8_cvt(s + (size_t)j * 8);
  } else {
    int i = (bid - cvtBlocks) * 256 + threadIdx.x;   // ((h*64)+q)*192+k
    int k = i % 192;
    int rest = i / 192;
    int q = rest & 63, h = rest >> 6;
    float v = -60.f;
    if (k < NTOK && q < WS2) {
      if (k < WS2) {
        int iq = q / 7, jq = q - iq * 7, ik = k / 7, jk = k - ik * 7;
        v = rpbT[((iq - ik + 6) * 13 + (jq - jk + 6)) * NHEAD + h];
      } else {
        v = rpbN[(h * WS2 + q) * NKEY + (k - WS2)];
      }
    }
    biasTab[i] = v * LOG2E;
  }
}

// ---- fast GEMM (bf16 A and Bt, global_load_lds staging, m97 structure) ----
// scale0 multiplies output 0 (sel==0) after bias add (used to pre-scale Q).
template <typename OT>
__global__ __launch_bounds__(256) void gemm_fast(
    const __bf16* __restrict__ A, const __bf16* __restrict__ Bt,
    const float* __restrict__ bias,
    OT* __restrict__ O0, OT* __restrict__ O1, OT* __restrict__ O2,
    int K, int NoutPer, int nxt, float scale0) {
  __shared__ __bf16 As[128 * 64];
  __shared__ __bf16 Bs[128 * 64];

  const int t = threadIdx.x;
  const int wv = t >> 6, ln = t & 63;
  const int lc = ln & 15, kg = (ln >> 4) * 8;
  const int wm = wv >> 1, wn = wv & 1;
  const int L = xcd_swizzle(blockIdx.x, gridDim.x);
  const int mt = L / nxt, nt = L - mt * nxt;
  const int m0 = mt * 128, n0 = nt * 128;

  const __bf16* ga = A + (size_t)(m0 + wv * 8 + (ln >> 3)) * K + (ln & 7) * 8;
  const __bf16* gb = Bt + (size_t)(n0 + wv * 8 + (ln >> 3)) * K + (ln & 7) * 8;

  f32x4 acc[4][4] = {};

  for (int kt = 0; kt < K; kt += 64) {
#pragma unroll
    for (int i = 0; i < 4; ++i) {
      gload16(ga + (size_t)(i * 32) * K + kt, As + (i * 32 + wv * 8) * 64);
      gload16(gb + (size_t)(i * 32) * K + kt, Bs + (i * 32 + wv * 8) * 64);
    }
    __syncthreads();
#pragma unroll
    for (int ks = 0; ks < 2; ++ks) {
      bf16x8 af[4], bb[4];
#pragma unroll
      for (int m = 0; m < 4; ++m)
        af[m] = *(const bf16x8*)&As[(wm * 64 + m * 16 + lc) * 64 + ks * 32 + kg];
#pragma unroll
      for (int n = 0; n < 4; ++n)
        bb[n] = *(const bf16x8*)&Bs[(wn * 64 + n * 16 + lc) * 64 + ks * 32 + kg];
#pragma unroll
      for (int m = 0; m < 4; ++m)
#pragma unroll
        for (int n = 0; n < 4; ++n)
          acc[m][n] = __builtin_amdgcn_mfma_f32_16x16x32_bf16(af[m], bb[n], acc[m][n], 0, 0, 0);
    }
    __syncthreads();
  }

  OT* outs[3] = {O0, O1, O2};
#pragma unroll
  for (int n = 0; n < 4; ++n) {
    int col = n0 + wn * 64 + n * 16 + lc;
    int sel = col / NoutPer;
    int c = col - sel * NoutPer;
    float bv = bias[col];
    float sc = (sel == 0) ? scale0 : 1.f;
    OT* op = outs[sel];
#pragma unroll
    for (int m = 0; m < 4; ++m) {
      int row = m0 + wm * 64 + m * 16 + (ln >> 4) * 4;
#pragma unroll
      for (int r = 0; r < 4; ++r)
        op[(size_t)(row + r) * NoutPer + c] = (OT)((acc[m][n][r] + bv) * sc);
    }
  }
}

// ---- fallback GEMM (f32/bf16 A reg-staged, optional qperm) ----
template <typename AT, typename OT>
__global__ __launch_bounds__(256) void gemm_bt(
    const AT* __restrict__ A, const float* __restrict__ Bt,
    const float* __restrict__ bias,
    OT* __restrict__ O0, OT* __restrict__ O1, OT* __restrict__ O2,
    int K, int NoutPer, int qPerm, int nxt, float scale0) {
  __shared__ __bf16 As[128 * 64];
  __shared__ __bf16 Bs[128 * 64];

  const int t = threadIdx.x;
  const int wv = t >> 6, ln = t & 63;
  const int lc = ln & 15, kg = (ln >> 4) * 8;
  const int wm = wv >> 1, wn = wv & 1;
  const int L = xcd_swizzle(blockIdx.x, gridDim.x);
  const int mt = L / nxt, nt = L - mt * nxt;
  const int m0 = mt * 128, n0 = nt * 128;
  const int srow = t >> 3, scol = (t & 7) * 8;

  f32x4 acc[4][4] = {};

  for (int kt = 0; kt < K; kt += 64) {
#pragma unroll
    for (int i = 0; i < 4; ++i) {
      int row = i * 32 + srow;
      *(bf16x8*)&As[row * 64 + scol] = load8_cvt(A + (size_t)(m0 + row) * K + kt + scol);
      *(bf16x8*)&Bs[row * 64 + scol] = load8_cvt(Bt + (size_t)(n0 + row) * K + kt + scol);
    }
    __syncthreads();
#pragma unroll
    for (int ks = 0; ks < 2; ++ks) {
      bf16x8 af[4], bb[4];
#pragma unroll
      for (int m = 0; m < 4; ++m)
        af[m] = *(const bf16x8*)&As[(wm * 64 + m * 16 + lc) * 64 + ks * 32 + kg];
#pragma unroll
      for (int n = 0; n < 4; ++n)
        bb[n] = *(const bf16x8*)&Bs[(wn * 64 + n * 16 + lc) * 64 + ks * 32 + kg];
#pragma unroll
      for (int m = 0; m < 4; ++m)
#pragma unroll
        for (int n = 0; n < 4; ++n)
          acc[m][n] = __builtin_amdgcn_mfma_f32_16x16x32_bf16(af[m], bb[n], acc[m][n], 0, 0, 0);
    }
    __syncthreads();
  }

  OT* outs[3] = {O0, O1, O2};
#pragma unroll
  for (int n = 0; n < 4; ++n) {
    int col = n0 + wn * 64 + n * 16 + lc;
    int sel = col / NoutPer;
    int c = col - sel * NoutPer;
    float bv = bias[col];
    float sc = (qPerm && sel == 0) ? scale0 : 1.f;
    OT* op = outs[sel];
    bool perm = qPerm && (sel == 0);
#pragma unroll
    for (int m = 0; m < 4; ++m) {
      int row = m0 + wm * 64 + m * 16 + (ln >> 4) * 4;
#pragma unroll
      for (int r = 0; r < 4; ++r) {
        int rr = row + r;
        int orow = perm ? qperm(rr) : rr;
        op[(size_t)orow * NoutPer + c] = (OT)((acc[m][n][r] + bv) * sc);
      }
    }
  }
}

// ---- one head's full compute (QK^T + softmax + PV + epilogue) ----
// Verified r16 numerics, moved into a function unchanged.
DEVINL void attn_head_compute(
    bf16x8 aq, const float* __restrict__ btab,
    const __bf16* Ks, const __bf16* Vt,
    int win, int hb, int wv, int lc, int lg,
    __bf16* __restrict__ Og) {
  // swapped QK^T: lane holds col q = wv*16+lc, rows k = nf*16 + lg*4 + r
  f32x4 s[12];
  __builtin_amdgcn_s_setprio(1);
#pragma unroll
  for (int nf = 0; nf < 12; ++nf) {
    bf16x8 kf = *(const bf16x8*)&Ks[(nf * 16 + lc) * 40 + lg * 8];
    f32x4 c = *(const f32x4*)&btab[nf * 16 + lg * 4];
    s[nf] = __builtin_amdgcn_mfma_f32_16x16x32_bf16(kf, aq, c, 0, 0, 0);
  }
  __builtin_amdgcn_s_setprio(0);

  // softmax (log2 domain, raw v_exp_f32)
  float mx = -1e30f;
#pragma unroll
  for (int nf = 0; nf < 12; ++nf)
#pragma unroll
    for (int r = 0; r < 4; ++r) mx = fmaxf(mx, s[nf][r]);
  mx = fmaxf(mx, __shfl_xor(mx, 16));
  mx = fmaxf(mx, __shfl_xor(mx, 32));

  float sum = 0.f;
#pragma unroll
  for (int nf = 0; nf < 12; ++nf)
#pragma unroll
    for (int r = 0; r < 4; ++r) {
      float e = fast_exp2(s[nf][r] - mx);
      s[nf][r] = e;
      sum += e;
    }
  sum += __shfl_xor(sum, 16);
  sum += __shfl_xor(sum, 32);
  float inv = 1.f / sum;

  // PV with in-register P handoff (permlane builtins — r16-verified).
  const int s0 = lc + ((lg & 1) << 5);
  const int s1 = s0 + 16;
  const bool lo = (lg < 2);
  f32x4 o[2] = {{}, {}};
  __builtin_amdgcn_s_setprio(1);
#pragma unroll
  for (int ks = 0; ks < 6; ++ks) {
    int na = 2 * ks, nb = 2 * ks + 1;
    unsigned la0 = pack2(s[na][0], s[na][1]);
    unsigned la1 = pack2(s[na][2], s[na][3]);
    unsigned lb0 = pack2(s[nb][0], s[nb][1]);
    unsigned lb1 = pack2(s[nb][2], s[nb][3]);
    u32x4 wvec;
#if HAVE_PERMLANE_SWAP
    {
      u32x2 r0 = __builtin_amdgcn_permlane32_swap(la0, lb0, false, false);
      u32x2 r1 = __builtin_amdgcn_permlane16_swap(r0[0], r0[1], false, false);
      u32x2 r2 = __builtin_amdgcn_permlane32_swap(la1, lb1, false, false);
      u32x2 r3 = __builtin_amdgcn_permlane16_swap(r2[0], r2[1], false, false);
      wvec[0] = r1[0];   // w0 = [A0,A2,B0,B2]
      wvec[1] = r3[0];   // w1
      wvec[2] = r1[1];   // w2 = [A1,A3,B1,B3]
      wvec[3] = r3[1];   // w3
    }
#else
    {
      unsigned xa0 = __shfl(la0, s0);
      unsigned xb0 = __shfl(lb0, s0);
      unsigned xa1 = __shfl(la1, s0);
      unsigned xb1 = __shfl(lb1, s0);
      unsigned ya0 = __shfl(la0, s1);
      unsigned yb0 = __shfl(lb0, s1);
      unsigned ya1 = __shfl(la1, s1);
      unsigned yb1 = __shfl(lb1, s1);
      wvec[0] = lo ? xa0 : xb0;
      wvec[1] = lo ? xa1 : xb1;
      wvec[2] = lo ? ya0 : yb0;
      wvec[3] = lo ? ya1 : yb1;
    }
#endif
    bf16x8 ap = __builtin_bit_cast(bf16x8, wvec);
#pragma unroll
    for (int nf = 0; nf < 2; ++nf) {
      int rowV = nf * 16 + lc;
      int cv = ks * 32 + lg * 8 + (rowV >> 3) * 16; if (cv >= 200) cv -= 200;
      bf16x8 bv = *(const bf16x8*)&Vt[rowV * 200 + cv];
      o[nf] = __builtin_amdgcn_mfma_f32_16x16x32_bf16(ap, bv, o[nf], 0, 0, 0);
    }
  }
  __builtin_amdgcn_s_setprio(0);

  // epilogue: output rows q = wv*16 + lg*4 + r; 1/sum via shfl
  float invr[4];
#pragma unroll
  for (int r = 0; r < 4; ++r) invr[r] = __shfl(inv, lg * 4 + r);

#pragma unroll
  for (int nf = 0; nf < 2; ++nf)
#pragma unroll
    for (int r = 0; r < 4; ++r) {
      int qo = wv * 16 + lg * 4 + r;
      if (qo < WS2)
        Og[(size_t)(win * WS2 + qo) * DIM + hb + nf * 16 + lc] =
            (__bf16)(o[nf][r] * invr[r]);
    }
}

// ---- attention v4: 2 heads per block (same window -> shared offsets) ----
// Pipeline: stage h0 -> barrier -> issue h1 global loads (regs) -> compute h0
// (hides HBM latency) -> barrier -> reg->LDS write h1 -> barrier -> compute h1.
// LDS = Ks[192][40] + Vt[32][200] = 28,160 B. Qg pre-scaled by SCALE*log2e;
// biasTab in log2e domain. Og window-ordered.
template <int QPIX>
__global__ __launch_bounds__(256, 4) void attn_win(
    const __bf16* __restrict__ Qg, const __bf16* __restrict__ Kg, const __bf16* __restrict__ Vg,
    const float* __restrict__ biasTab,
    __bf16* __restrict__ Og) {
  __shared__ __bf16 Ks[192 * 40];   // K row-major, stride 40 (bank-spread)
  __shared__ __bf16 Vt[32 * 200];   // V^T rotated: col = (token + (d>>3)*16) % 200

  const int S = xcd_swizzle(blockIdx.x, ATTN_GRID);
  const int win = S / (NHEAD / 2);
  const int hp = S - win * (NHEAD / 2);
  const int h0 = hp * 2, h1 = h0 + 1;
  const int hb0 = h0 * HDIM, hb1 = h1 * HDIM;
  const int b = win / (NWY * NWX);
  const int wrem = win - b * (NWY * NWX);
  const int wy = wrem / NWX, wx = wrem - wy * NWX;
  const int y0 = wy * WSZ, x0 = wx * WSZ;

  const int t = threadIdx.x;
  const int wv = t >> 6, ln = t & 63;
  const int lc = ln & 15, lg = ln >> 4;
  const int q = wv * 16 + lc;        // this lane's q (output col in swapped QK^T)

  // per-thread staging offsets (token base + ch*8, WITHOUT head column)
  int offs[3]; bool val[3]; int toks[3], chs[3];
#pragma unroll
  for (int it = 0; it < 3; ++it) {
    int idx = t + it * 256;
    int token = idx >> 2, ch = idx & 3;
    int pk = TOKTAB.v[token];
    int yy = y0 + (pk >> 5) - 8;
    int xx = x0 + (pk & 31) - 8;
    if (yy < 0) yy += HH; else if (yy >= HH) yy -= HH;
    if (xx < 0) xx += WW; else if (xx >= WW) xx -= WW;
    offs[it] = ((b * HH + yy) * WW + xx) * DIM + ch * 8;
    val[it] = token < NTOK;
    toks[it] = token; chs[it] = ch;
  }

  // Q base offset (head-independent)
  int qoff = 0;
  if (q < WS2) {
    if (QPIX) {
      int pk = TOKTAB.v[q];
      int yy = y0 + (pk >> 5) - 8, xx = x0 + (pk & 31) - 8;
      qoff = ((b * HH + yy) * WW + xx) * DIM;
    } else {
      qoff = (win * WS2 + q) * DIM;
    }
  }

  // ---- head 0: load K/V into regs, write LDS ----
  bf16x8 kv[3], vv[3];
#pragma unroll
  for (int it = 0; it < 3; ++it) {
    kv[it] = bf16x8{}; vv[it] = bf16x8{};
    if (val[it]) {
      kv[it] = *(const bf16x8*)(Kg + (size_t)offs[it] + hb0);
      vv[it] = *(const bf16x8*)(Vg + (size_t)offs[it] + hb0);
    }
  }
  bf16x8 aq0 = {};
  if (q < WS2) aq0 = *(const bf16x8*)(Qg + (size_t)qoff + hb0 + lg * 8);

#pragma unroll
  for (int it = 0; it < 3; ++it) {
    *(bf16x8*)&Ks[toks[it] * 40 + chs[it] * 8] = kv[it];
    int col2 = toks[it] + chs[it] * 16; if (col2 >= 200) col2 -= 200;
#pragma unroll
    for (int e = 0; e < 8; ++e)
      Vt[(chs[it] * 8 + e) * 200 + col2] = vv[it][e];
  }
  __syncthreads();                       // LDS#0 ready

  // ---- issue head-1 global loads EARLY (latency hides under compute h0) ----
#pragma unroll
  for (int it = 0; it < 3; ++it) {
    kv[it] = bf16x8{}; vv[it] = bf16x8{};
    if (val[it]) {
      kv[it] = *(const bf16x8*)(Kg + (size_t)offs[it] + hb1);
      vv[it] = *(const bf16x8*)(Vg + (size_t)offs[it] + hb1);
    }
  }
  bf16x8 aq1 = {};
  if (q < WS2) aq1 = *(const bf16x8*)(Qg + (size_t)qoff + hb1 + lg * 8);

  // ---- compute head 0 ----
  attn_head_compute(aq0, biasTab + ((size_t)h0 * 64 + q) * 192,
                    Ks, Vt, win, hb0, wv, lc, lg, Og);
  __syncthreads();                       // all waves done reading LDS#0

  // ---- write head-1 LDS (vmcnt wait lands here), compute head 1 ----
#pragma unroll
  for (int it = 0; it < 3; ++it) {
    *(bf16x8*)&Ks[toks[it] * 40 + chs[it] * 8] = kv[it];
    int col2 = toks[it] + chs[it] * 16; if (col2 >= 200) col2 -= 200;
#pragma unroll
    for (int e = 0; e < 8; ++e)
      Vt[(chs[it] * 8 + e) * 200 + col2] = vv[it][e];
  }
  __syncthreads();

  attn_head_compute(aq1, biasTab + ((size_t)h1 * 64 + q) * 192,
                    Ks, Vt, win, hb1, wv, lc, lg, Og);
}

extern "C" void kernel_launch(void* const* d_in, const int* in_sizes, int n_in,
                              void* d_out, int out_size, void* d_ws, size_t ws_size,
                              hipStream_t stream) {
  const float* x      = (const float*)d_in[0];
  const float* w_qkv  = (const float*)d_in[1];
  const float* b_qkv  = (const float*)d_in[2];
  const float* w_proj = (const float*)d_in[3];
  const float* b_proj = (const float*)d_in[4];
  const float* rpbT   = (const float*)d_in[5];
  const float* rpbN   = (const float*)d_in[6];

  float* out = (float*)d_out;
  __bf16* k_ws = (__bf16*)d_out;           // d_out = 2 bf16 planes (K, V)
  __bf16* v_ws = k_ws + PLANE;

  const size_t fast_elems = 2 * PLANE + NQKV + NPROJ;
  const size_t fast_ws_bytes = fast_elems * 2 + BIAS_ELEMS * 4;   // ~88.5 MB
  const float qscale = SCALE * LOG2E;

  if (ws_size >= fast_ws_bytes) {
    // FAST PATH: pre-convert to bf16, global_load_lds GEMMs, no row permute.
    __bf16* xo_bf   = (__bf16*)d_ws;       // x_bf during gemm1; O plane after
    __bf16* q_bf    = xo_bf + PLANE;       // Q, pixel-ordered, pre-scaled
    __bf16* wqkv_b  = q_bf + PLANE;
    __bf16* wproj_b = wqkv_b + NQKV;
    float*  biasTab = (float*)(wproj_b + NPROJ);

    cvt_bias<<<dim3(CVT_GRID + BIAS_GRID), 256, 0, stream>>>(
        x, w_qkv, w_proj, xo_bf, wqkv_b, wproj_b, rpbT, rpbN, biasTab, CVT_GRID);

    gemm_fast<__bf16><<<dim3((1152 / 128) * (MTOT / 128)), 256, 0, stream>>>(
        xo_bf, wqkv_b, b_qkv, q_bf, k_ws, v_ws, DIM, DIM, 1152 / 128, qscale);

    attn_win<1><<<dim3(ATTN_GRID), 256, 0, stream>>>(
        q_bf, k_ws, v_ws, biasTab, xo_bf);   // O overwrites dead x_bf

    gemm_fast<float><<<dim3((384 / 128) * (MTOT / 128)), 256, 0, stream>>>(
        xo_bf, wproj_b, b_proj, out, out, out, DIM, DIM, 384 / 128, 1.f);
  } else {
    // FALLBACK: f32 reg-staged GEMM1 with qperm epilogue (Q pre-scaled).
    __bf16* qo_ws   = (__bf16*)d_ws;
    float*  biasTab = (float*)(qo_ws + PLANE);

    cvt_bias<<<dim3(BIAS_GRID), 256, 0, stream>>>(
        x, w_qkv, w_proj, nullptr, nullptr, nullptr, rpbT, rpbN, biasTab, 0);

    gemm_bt<float, __bf16><<<dim3((1152 / 128) * (MTOT / 128)), 256, 0, stream>>>(
        x, w_qkv, b_qkv, qo_ws, k_ws, v_ws, DIM, DIM, 1, 1152 / 128, qscale);

    attn_win<0><<<dim3(ATTN_GRID), 256, 0, stream>>>(
        qo_ws, k_ws, v_ws, biasTab, qo_ws);

    gemm_bt<__bf16, float><<<dim3((384 / 128) * (MTOT / 128)), 256, 0, stream>>>(
        qo_ws, w_proj, b_proj, out, out, out, DIM, DIM, 0, 384 / 128, 1.f);
  }
}